// Round 5
// baseline (486.524 us; speedup 1.0000x reference)
//
#include <hip/hip_runtime.h>
#include <hip/hip_bf16.h>

typedef unsigned short u16;
typedef __attribute__((ext_vector_type(8))) short bf16x8;          // 8 x 16-bit payload regs
typedef __attribute__((ext_vector_type(8))) _Float16 f16x8;
typedef __attribute__((ext_vector_type(8))) unsigned short u16x8;
typedef __attribute__((ext_vector_type(4))) float f32x4;

__device__ __forceinline__ u16 f2b(float f) {
  _Float16 h = (_Float16)f;
  return __builtin_bit_cast(u16, h);
}

__device__ __forceinline__ f32x4 mfma16(bf16x8 a, bf16x8 b, f32x4 c) {
  return __builtin_amdgcn_mfma_f32_16x16x32_f16(
      __builtin_bit_cast(f16x8, a), __builtin_bit_cast(f16x8, b), c, 0, 0, 0);
}

__device__ __forceinline__ float fexp2(float x) {   // 2^x, exact ISA op
  float r; asm("v_exp_f32 %0, %1" : "=v"(r) : "v"(x)); return r;
}

#define GLD16(dst, src) __builtin_amdgcn_global_load_lds( \
    (const __attribute__((address_space(1))) void*)(src), \
    (__attribute__((address_space(3))) void*)(dst), 16, 0, 0)

// ---------------------------------------------------------------------------
// pack_x: A1[n][k] f16, k<1024 from x_r, else x_i.  (n = b*2048+l token)
// ---------------------------------------------------------------------------
__global__ void pack_x_kernel(u16* __restrict__ A1, const float* __restrict__ xr,
                              const float* __restrict__ xi) {
  const int id = blockIdx.x * 256 + threadIdx.x;
  const size_t k8 = (size_t)id * 8;
  const int n = (int)(k8 >> 11);
  const int kk = (int)(k8 & 2047);
  const float* src = (kk < 1024) ? (xr + (size_t)n * 1024 + kk)
                                 : (xi + (size_t)n * 1024 + (kk - 1024));
  float4 a = *(const float4*)src;
  float4 c = *(const float4*)(src + 4);
  u16x8 o;
  o[0] = f2b(a.x); o[1] = f2b(a.y); o[2] = f2b(a.z); o[3] = f2b(a.w);
  o[4] = f2b(c.x); o[5] = f2b(c.y); o[6] = f2b(c.z); o[7] = f2b(c.w);
  *(u16x8*)(A1 + k8) = o;
}

// ---------------------------------------------------------------------------
// pack_w_all: batched weight packer. Slab s (0..7): wset = s>>1 (q,k,v,o),
// isim = s&1.  real: [Wr | -Wi], bias br-bi.  imag: [Wi | Wr], bias br+bi.
// s<6 -> B1 slab s;  s>=6 -> B2 slab s-6.
// ---------------------------------------------------------------------------
struct PWArgs {
  const float* Wr[4]; const float* Wi[4];
  const float* br[4]; const float* bi[4];
};

__global__ void pack_w_all(PWArgs a, int sbase, u16* __restrict__ B1,
                           u16* __restrict__ B2, float* __restrict__ bias1,
                           float* __restrict__ bias2) {
  const int s = sbase + blockIdx.y;
  const int wi = s >> 1, isim = s & 1;
  u16* dst = (s < 6) ? (B1 + (size_t)s * (1024 * 2048))
                     : (B2 + (size_t)(s - 6) * (1024 * 2048));
  float* biasDst = (s < 6) ? (bias1 + s * 1024) : (bias2 + (s - 6) * 1024);
  const int row = blockIdx.x;
  const int kk = threadIdx.x * 8;
  const int half = kk >> 10;
  const int kloc = kk & 1023;
  const float* W = (half == 0) ? (isim ? a.Wi[wi] : a.Wr[wi])
                               : (isim ? a.Wr[wi] : a.Wi[wi]);
  const float sgn = (half == 1 && !isim) ? -1.f : 1.f;
  const float* src = W + (size_t)row * 1024 + kloc;
  float4 x = *(const float4*)src;
  float4 c = *(const float4*)(src + 4);
  u16x8 o;
  o[0] = f2b(sgn * x.x); o[1] = f2b(sgn * x.y); o[2] = f2b(sgn * x.z); o[3] = f2b(sgn * x.w);
  o[4] = f2b(sgn * c.x); o[5] = f2b(sgn * c.y); o[6] = f2b(sgn * c.z); o[7] = f2b(sgn * c.w);
  *(u16x8*)(dst + (size_t)row * 2048 + kk) = o;
  if (threadIdx.x == 0)
    biasDst[row] = isim ? (a.br[wi][row] + a.bi[wi][row])
                        : (a.br[wi][row] - a.bi[wi][row]);
}

// ---------------------------------------------------------------------------
// GEMM: C[4096][N] = A[4096][2048] * B[N][2048]^T + bias[N]
// 128x128 tile, 4 waves (2x2) of 64x64, BK=64, 16x16x32 f16 MFMA,
// global_load_lds(16B) staging with XOR chunk swizzle.
// MODE 0 (QKV): j<4096 -> linear f16 planes (qr,qi,kr,ki) of qkv;
//               j>=4096 -> V written TRANSPOSED into vt[ri][bh*64+d][tok].
// MODE 1 (O):   f32 planes of d_out.
// ---------------------------------------------------------------------------
template<int MODE>
__global__ __launch_bounds__(256) void gemm_bt(const u16* __restrict__ A,
                                               const u16* __restrict__ Bw,
                                               const float* __restrict__ bias,
                                               void* __restrict__ outp,
                                               u16* __restrict__ vtp) {
  constexpr int K = 2048;
  __shared__ __align__(16) u16 As[128 * 64];
  __shared__ __align__(16) u16 Bs[128 * 64];
  const int tid = threadIdx.x;
  const int w = tid >> 6, l = tid & 63;
  const int l15 = l & 15, lhi = l >> 4;
  const int m0 = blockIdx.y * 128, n0 = blockIdx.x * 128;
  const int wm = w >> 1, wn = w & 1;
  f32x4 acc[4][4] = {};
  for (int kt = 0; kt < K; kt += 64) {
#pragma unroll
    for (int it = 0; it < 4; ++it) {
      const int grp = it * 4 + w;
      const int cl = grp * 64 + l;
      const int r = cl >> 3;
      const int g = (cl & 7) ^ (r & 7);
      GLD16(As + grp * 512, A + (size_t)(m0 + r) * K + kt + g * 8);
      GLD16(Bs + grp * 512, Bw + (size_t)(n0 + r) * K + kt + g * 8);
    }
    __syncthreads();
#pragma unroll
    for (int ks = 0; ks < 2; ++ks) {
      const int c = ks * 4 + lhi;
      bf16x8 af[4], bfr[4];
#pragma unroll
      for (int mf = 0; mf < 4; ++mf) {
        const int r = wm * 64 + mf * 16 + l15;
        af[mf] = *(const bf16x8*)&As[r * 64 + ((c ^ (r & 7)) << 3)];
      }
#pragma unroll
      for (int nf = 0; nf < 4; ++nf) {
        const int r = wn * 64 + nf * 16 + l15;
        bfr[nf] = *(const bf16x8*)&Bs[r * 64 + ((c ^ (r & 7)) << 3)];
      }
#pragma unroll
      for (int mf = 0; mf < 4; ++mf)
#pragma unroll
        for (int nf = 0; nf < 4; ++nf)
          acc[mf][nf] = mfma16(af[mf], bfr[nf], acc[mf][nf]);
    }
    __syncthreads();
  }
#pragma unroll
  for (int nf = 0; nf < 4; ++nf) {
    const int j = n0 + wn * 64 + nf * 16 + l15;
    const float bv = bias[j];
    if constexpr (MODE == 1) {
      const size_t obase = (size_t)(j >> 10) * (4096 * 1024) + (j & 1023);
#pragma unroll
      for (int mf = 0; mf < 4; ++mf)
#pragma unroll
        for (int i = 0; i < 4; ++i) {
          const int row = m0 + wm * 64 + mf * 16 + lhi * 4 + i;
          ((float*)outp)[obase + (size_t)row * 1024] = acc[mf][nf][i] + bv;
        }
    } else {
      if (j < 4096) {               // q,k planes, linear (uniform branch)
        const size_t obase = (size_t)(j >> 10) * (4096 * 1024) + (j & 1023);
#pragma unroll
        for (int mf = 0; mf < 4; ++mf)
#pragma unroll
          for (int i = 0; i < 4; ++i) {
            const int row = m0 + wm * 64 + mf * 16 + lhi * 4 + i;
            ((u16*)outp)[obase + (size_t)row * 1024] = f2b(acc[mf][nf][i] + bv);
          }
      } else {                      // v -> transposed vt[ri][(b*16+h)*64+d][tok]
        const int jv = j - 4096;
        const size_t vb = (size_t)(jv >> 10) * 4194304 +
                          (size_t)((jv >> 6) & 15) * 131072 +
                          (size_t)(jv & 63) * 2048;
#pragma unroll
        for (int mf = 0; mf < 4; ++mf)
#pragma unroll
          for (int i = 0; i < 4; ++i) {
            const int row = m0 + wm * 64 + mf * 16 + lhi * 4 + i;
            const int b2 = row >> 11, tok = row & 2047;
            vtp[vb + (size_t)b2 * 2097152 + tok] = f2b(acc[mf][nf][i] + bv);
          }
      }
    }
  }
}

// ---------------------------------------------------------------------------
// Flash interference attention, round 5:
//  - KVBLK=32, K/V double-buffered (32KB) + P strip (5KB) -> ~38KB LDS
//    -> 4 blocks/CU (16 waves, ~50% occupancy), grid = exactly 4/CU.
//  - each wave stages one matrix per tile (Kr/Ki: 32x64; Vr/Vi: 64x32,
//    conflict-free XOR swizzles, both-sides discipline).
//  - exp2-domain softmax (v_exp_f32 direct), defer-max THR=11 (log2),
//    deferred final sum reduce, setprio around MFMA clusters.
// grid (32 q-tiles, 32 bh). 4 waves x 16 q-rows.
// Writes A2[4096][2048] f16: c_r cols 0..1023, c_i cols 1024..2047.
// ---------------------------------------------------------------------------
__global__ __launch_bounds__(256, 4) void attn_kernel(const u16* __restrict__ qkv,
                                                      const u16* __restrict__ vt,
                                                      const float* __restrict__ mask,
                                                      u16* __restrict__ A2) {
  __shared__ __align__(16) u16 KVb[2][4][2048];   // [buf][Kr,Ki (32x64) | Vr,Vi (64x32)]
  __shared__ __align__(16) u16 Pl[4][16 * 40];
  const int tid = threadIdx.x, w = tid >> 6, l = tid & 63;
  const int l15 = l & 15, lhi = l >> 4;
  const int q0 = blockIdx.x * 64;
  const int bh = blockIdx.y;
  const int b = bh >> 4, h = bh & 15;
  const size_t M1 = (size_t)4096 * 1024;
  const u16* qr_b = qkv;
  const u16* qi_b = qkv + M1;
  const u16* kr_b = qkv + 2 * M1;
  const u16* ki_b = qkv + 3 * M1;
  const u16* vtr = vt;
  const u16* vti = vt + (size_t)32 * 64 * 2048;
  constexpr float LOG2E = 1.4426950408889634f;
  constexpr float C2 = 0.015625f * LOG2E;   // 1/HD in log2 domain

  const size_t qrow = (size_t)(b * 2048 + q0 + w * 16 + l15) * 1024 + h * 64;
  bf16x8 qr[2], qi[2], qrn[2];
#pragma unroll
  for (int ks = 0; ks < 2; ++ks) {
    qr[ks] = *(const bf16x8*)&qr_b[qrow + ks * 32 + lhi * 8];
    qi[ks] = *(const bf16x8*)&qi_b[qrow + ks * 32 + lhi * 8];
    qrn[ks] = qr[ks] ^ (short)0x8000;   // -Qr (f16 sign flip)
  }
  float mrow[4], srow[4];
  f32x4 o_r[4] = {}, o_i[4] = {};
#pragma unroll
  for (int i = 0; i < 4; ++i) { mrow[i] = -1e30f; srow[i] = 0.f; }
  u16* Pw = Pl[w];

  auto STAGE = [&](int tile, int bufi) {
    const int k0s = tile * 32;
    if (w < 2) {                       // K mats: [32 keys][64 d]
      const u16* src = w ? ki_b : kr_b;
      u16* dstb = &KVb[bufi][w][0];
#pragma unroll
      for (int it = 0; it < 4; ++it) {
        const int cl = it * 64 + l;
        const int r = cl >> 3;
        const int g = (cl & 7) ^ (r & 7);
        GLD16(dstb + it * 512, src + (size_t)(b * 2048 + k0s + r) * 1024 + h * 64 + g * 8);
      }
    } else {                           // V mats: [64 d][32 tok]
      const u16* src = (w == 3) ? vti : vtr;
      u16* dstb = &KVb[bufi][w][0];
#pragma unroll
      for (int it = 0; it < 4; ++it) {
        const int cl = it * 64 + l;
        const int r = cl >> 2;
        const int g = (cl & 3) ^ ((r >> 1) & 3);
        GLD16(dstb + it * 512, src + (size_t)(bh * 64 + r) * 2048 + k0s + g * 8);
      }
    }
  };

  STAGE(0, 0);
#pragma unroll 2
  for (int kt = 0; kt < 64; ++kt) {
    const int cur = kt & 1;
    const int k0 = kt * 32;
    __syncthreads();                   // implicit vmcnt(0): buf[cur] ready
    if (kt < 63) STAGE(kt + 1, cur ^ 1);
    const u16* Kr = &KVb[cur][0][0];
    const u16* Ki = &KVb[cur][1][0];
    const u16* Vr = &KVb[cur][2][0];
    const u16* Vi = &KVb[cur][3][0];
    // ---- scores ----
    f32x4 sr[2] = {}, si[2] = {};
    __builtin_amdgcn_s_setprio(1);
#pragma unroll
    for (int nf = 0; nf < 2; ++nf) {
      const int rk = nf * 16 + l15;
      const int sw = rk & 7;
#pragma unroll
      for (int ks = 0; ks < 2; ++ks) {
        const int c = ks * 4 + lhi;
        const int off = rk * 64 + ((c ^ sw) << 3);
        bf16x8 kfr = *(const bf16x8*)&Kr[off];
        bf16x8 kfi = *(const bf16x8*)&Ki[off];
        sr[nf] = mfma16(qr[ks], kfr, sr[nf]);
        sr[nf] = mfma16(qi[ks], kfi, sr[nf]);
        si[nf] = mfma16(qi[ks], kfr, si[nf]);
        si[nf] = mfma16(qrn[ks], kfi, si[nf]);
      }
    }
    __builtin_amdgcn_s_setprio(0);
    float t[2][4];
#pragma unroll
    for (int nf = 0; nf < 2; ++nf) {
      const float mkl = mask[b * 2048 + k0 + nf * 16 + l15] * LOG2E;
#pragma unroll
      for (int i = 0; i < 4; ++i) {
        const float ss = fmaf(si[nf][i], si[nf][i], sr[nf][i] * sr[nf][i]);
        t[nf][i] = fmaf(ss, C2, mkl);
      }
    }
    // ---- per-tile row max ----
    float pmax[4];
#pragma unroll
    for (int i = 0; i < 4; ++i) {
      float v = fmaxf(t[0][i], t[1][i]);
      v = fmaxf(v, __shfl_xor(v, 1, 64));
      v = fmaxf(v, __shfl_xor(v, 2, 64));
      v = fmaxf(v, __shfl_xor(v, 4, 64));
      v = fmaxf(v, __shfl_xor(v, 8, 64));
      pmax[i] = v;
    }
    bool grow = false;
#pragma unroll
    for (int i = 0; i < 4; ++i) grow |= (pmax[i] > mrow[i] + 11.f);
    if (__any(grow)) {
#pragma unroll
      for (int i = 0; i < 4; ++i) {
        const float mn = fmaxf(mrow[i], pmax[i]);
        const float sc = fexp2(mrow[i] - mn);
        mrow[i] = mn;
        srow[i] *= sc;
#pragma unroll
        for (int nf = 0; nf < 4; ++nf) { o_r[nf][i] *= sc; o_i[nf][i] *= sc; }
      }
    }
    float p[2][4];
#pragma unroll
    for (int nf = 0; nf < 2; ++nf)
#pragma unroll
      for (int i = 0; i < 4; ++i) {
        p[nf][i] = fexp2(t[nf][i] - mrow[i]);   // bounded by 2^11
        srow[i] += p[nf][i];
      }
    // ---- P repack via per-wave LDS strip, then PV ----
#pragma unroll
    for (int nf = 0; nf < 2; ++nf)
#pragma unroll
      for (int i = 0; i < 4; ++i)
        Pw[(lhi * 4 + i) * 40 + nf * 16 + l15] = f2b(p[nf][i]);
    bf16x8 pa = *(const bf16x8*)&Pw[l15 * 40 + lhi * 8];
    __builtin_amdgcn_s_setprio(1);
#pragma unroll
    for (int nf = 0; nf < 4; ++nf) {
      const int d = nf * 16 + l15;
      const int off = d * 32 + ((lhi ^ ((d >> 1) & 3)) << 3);
      bf16x8 vfr = *(const bf16x8*)&Vr[off];
      bf16x8 vfi = *(const bf16x8*)&Vi[off];
      o_r[nf] = mfma16(pa, vfr, o_r[nf]);
      o_i[nf] = mfma16(pa, vfi, o_i[nf]);
    }
    __builtin_amdgcn_s_setprio(0);
  }
  // ---- final row-sum reduce + normalize + store ----
  float inv[4];
#pragma unroll
  for (int i = 0; i < 4; ++i) {
    float v = srow[i];
    v += __shfl_xor(v, 1, 64);
    v += __shfl_xor(v, 2, 64);
    v += __shfl_xor(v, 4, 64);
    v += __shfl_xor(v, 8, 64);
    inv[i] = 1.f / v;
  }
  const int rowbase = b * 2048 + q0 + w * 16 + lhi * 4;
#pragma unroll
  for (int nf = 0; nf < 4; ++nf) {
    const int col = h * 64 + nf * 16 + l15;
#pragma unroll
    for (int i = 0; i < 4; ++i) {
      const size_t rw = (size_t)(rowbase + i) * 2048;
      A2[rw + col] = f2b(o_r[nf][i] * inv[i]);
      A2[rw + 1024 + col] = f2b(o_i[nf][i] * inv[i]);
    }
  }
}

// ---------------------------------------------------------------------------
extern "C" void kernel_launch(void* const* d_in, const int* in_sizes, int n_in,
                              void* d_out, int out_size, void* d_ws, size_t ws_size,
                              hipStream_t stream) {
  (void)in_sizes; (void)n_in; (void)out_size; (void)ws_size;
  const float* x_r  = (const float*)d_in[0];
  const float* x_i  = (const float*)d_in[1];
  const float* mask = (const float*)d_in[2];

  PWArgs pw;
  pw.Wr[0] = (const float*)d_in[3];  pw.br[0] = (const float*)d_in[4];
  pw.Wi[0] = (const float*)d_in[5];  pw.bi[0] = (const float*)d_in[6];
  pw.Wr[1] = (const float*)d_in[7];  pw.br[1] = (const float*)d_in[8];
  pw.Wi[1] = (const float*)d_in[9];  pw.bi[1] = (const float*)d_in[10];
  pw.Wr[2] = (const float*)d_in[11]; pw.br[2] = (const float*)d_in[12];
  pw.Wi[2] = (const float*)d_in[13]; pw.bi[2] = (const float*)d_in[14];
  pw.Wr[3] = (const float*)d_in[15]; pw.br[3] = (const float*)d_in[16];
  pw.Wi[3] = (const float*)d_in[17]; pw.bi[3] = (const float*)d_in[18];

  char* ws = (char*)d_ws;
  u16* A     = (u16*)(ws);                  // 16 MB: A1, later A2
  u16* B1    = (u16*)(ws + (16u << 20));    // 24 MB packed QKV weights (dead after gemm1)
  u16* B2    = (u16*)(ws + (16u << 20));    // 8 MB packed O weights (packed after gemm1)
  u16* qkvp  = (u16*)(ws + (40u << 20));    // 32 MB: qr,qi,kr,ki planes
  u16* vtp   = (u16*)(ws + (72u << 20));    // 16 MB: V transposed [2][32bh][64][2048]
  float* bias1 = (float*)(ws + (88u << 20));
  float* bias2 = (float*)(ws + (88u << 20) + (1u << 15));

  pack_x_kernel<<<4096, 256, 0, stream>>>(A, x_r, x_i);
  pack_w_all<<<dim3(1024, 6), 256, 0, stream>>>(pw, 0, B1, B2, bias1, bias2);

  gemm_bt<0><<<dim3(48, 32), 256, 0, stream>>>(A, B1, bias1, qkvp, vtp);

  pack_w_all<<<dim3(1024, 2), 256, 0, stream>>>(pw, 6, B1, B2, bias1, bias2);

  attn_kernel<<<dim3(32, 32), 256, 0, stream>>>(qkvp, vtp, mask, A);

  gemm_bt<1><<<dim3(16, 32), 256, 0, stream>>>(A, B2, bias2, d_out, nullptr);
}

// Round 6
// 422.492 us; speedup vs baseline: 1.1516x; 1.1516x over previous
//
#include <hip/hip_runtime.h>
#include <hip/hip_bf16.h>

typedef unsigned short u16;
typedef __attribute__((ext_vector_type(8))) short bf16x8;          // 8 x 16-bit payload regs
typedef __attribute__((ext_vector_type(8))) _Float16 f16x8;
typedef __attribute__((ext_vector_type(2))) _Float16 f16x2;
typedef __attribute__((ext_vector_type(8))) unsigned short u16x8;
typedef __attribute__((ext_vector_type(4))) float f32x4;
typedef __attribute__((ext_vector_type(16))) float f32x16;

__device__ __forceinline__ u16 f2b(float f) {
  _Float16 h = (_Float16)f;
  return __builtin_bit_cast(u16, h);
}

__device__ __forceinline__ f32x4 mfma16(bf16x8 a, bf16x8 b, f32x4 c) {
  return __builtin_amdgcn_mfma_f32_16x16x32_f16(
      __builtin_bit_cast(f16x8, a), __builtin_bit_cast(f16x8, b), c, 0, 0, 0);
}

__device__ __forceinline__ f32x16 mfma32(bf16x8 a, bf16x8 b, f32x16 c) {
  return __builtin_amdgcn_mfma_f32_32x32x16_f16(
      __builtin_bit_cast(f16x8, a), __builtin_bit_cast(f16x8, b), c, 0, 0, 0);
}

__device__ __forceinline__ float fexp2(float x) {   // 2^x, exact ISA op
  float r; asm("v_exp_f32 %0, %1" : "=v"(r) : "v"(x)); return r;
}

#define GLD16(dst, src) __builtin_amdgcn_global_load_lds( \
    (const __attribute__((address_space(1))) void*)(src), \
    (__attribute__((address_space(3))) void*)(dst), 16, 0, 0)

// ---------------------------------------------------------------------------
// pack_x: A1[n][k] f16, k<1024 from x_r, else x_i.  (n = b*2048+l token)
// ---------------------------------------------------------------------------
__global__ void pack_x_kernel(u16* __restrict__ A1, const float* __restrict__ xr,
                              const float* __restrict__ xi) {
  const int id = blockIdx.x * 256 + threadIdx.x;
  const size_t k8 = (size_t)id * 8;
  const int n = (int)(k8 >> 11);
  const int kk = (int)(k8 & 2047);
  const float* src = (kk < 1024) ? (xr + (size_t)n * 1024 + kk)
                                 : (xi + (size_t)n * 1024 + (kk - 1024));
  float4 a = *(const float4*)src;
  float4 c = *(const float4*)(src + 4);
  u16x8 o;
  o[0] = f2b(a.x); o[1] = f2b(a.y); o[2] = f2b(a.z); o[3] = f2b(a.w);
  o[4] = f2b(c.x); o[5] = f2b(c.y); o[6] = f2b(c.z); o[7] = f2b(c.w);
  *(u16x8*)(A1 + k8) = o;
}

// ---------------------------------------------------------------------------
// pack_w_all: batched weight packer. Slab s (0..7): wset = s>>1 (q,k,v,o),
// isim = s&1.  real: [Wr | -Wi], bias br-bi.  imag: [Wi | Wr], bias br+bi.
// ---------------------------------------------------------------------------
struct PWArgs {
  const float* Wr[4]; const float* Wi[4];
  const float* br[4]; const float* bi[4];
};

__global__ void pack_w_all(PWArgs a, int sbase, u16* __restrict__ B1,
                           u16* __restrict__ B2, float* __restrict__ bias1,
                           float* __restrict__ bias2) {
  const int s = sbase + blockIdx.y;
  const int wi = s >> 1, isim = s & 1;
  u16* dst = (s < 6) ? (B1 + (size_t)s * (1024 * 2048))
                     : (B2 + (size_t)(s - 6) * (1024 * 2048));
  float* biasDst = (s < 6) ? (bias1 + s * 1024) : (bias2 + (s - 6) * 1024);
  const int row = blockIdx.x;
  const int kk = threadIdx.x * 8;
  const int half = kk >> 10;
  const int kloc = kk & 1023;
  const float* W = (half == 0) ? (isim ? a.Wi[wi] : a.Wr[wi])
                               : (isim ? a.Wr[wi] : a.Wi[wi]);
  const float sgn = (half == 1 && !isim) ? -1.f : 1.f;
  const float* src = W + (size_t)row * 1024 + kloc;
  float4 x = *(const float4*)src;
  float4 c = *(const float4*)(src + 4);
  u16x8 o;
  o[0] = f2b(sgn * x.x); o[1] = f2b(sgn * x.y); o[2] = f2b(sgn * x.z); o[3] = f2b(sgn * x.w);
  o[4] = f2b(sgn * c.x); o[5] = f2b(sgn * c.y); o[6] = f2b(sgn * c.z); o[7] = f2b(sgn * c.w);
  *(u16x8*)(dst + (size_t)row * 2048 + kk) = o;
  if (threadIdx.x == 0)
    biasDst[row] = isim ? (a.br[wi][row] + a.bi[wi][row])
                        : (a.br[wi][row] - a.bi[wi][row]);
}

// ---------------------------------------------------------------------------
// GEMM: C[4096][N] = A[4096][2048] * B[N][2048]^T + bias[N]
// 128x128 tile, 4 waves (2x2) of 64x64, BK=64, 16x16x32 f16 MFMA,
// global_load_lds(16B) staging with XOR chunk swizzle.
// MODE 0 (QKV): j<4096 -> linear f16 planes (qr,qi,kr,ki) of qkv;
//               j>=4096 -> V written TRANSPOSED into vt[ri][bh*64+d][tok].
// MODE 1 (O):   f32 planes of d_out.
// ---------------------------------------------------------------------------
template<int MODE>
__global__ __launch_bounds__(256) void gemm_bt(const u16* __restrict__ A,
                                               const u16* __restrict__ Bw,
                                               const float* __restrict__ bias,
                                               void* __restrict__ outp,
                                               u16* __restrict__ vtp) {
  constexpr int K = 2048;
  __shared__ __align__(16) u16 As[128 * 64];
  __shared__ __align__(16) u16 Bs[128 * 64];
  const int tid = threadIdx.x;
  const int w = tid >> 6, l = tid & 63;
  const int l15 = l & 15, lhi = l >> 4;
  const int m0 = blockIdx.y * 128, n0 = blockIdx.x * 128;
  const int wm = w >> 1, wn = w & 1;
  f32x4 acc[4][4] = {};
  for (int kt = 0; kt < K; kt += 64) {
#pragma unroll
    for (int it = 0; it < 4; ++it) {
      const int grp = it * 4 + w;
      const int cl = grp * 64 + l;
      const int r = cl >> 3;
      const int g = (cl & 7) ^ (r & 7);
      GLD16(As + grp * 512, A + (size_t)(m0 + r) * K + kt + g * 8);
      GLD16(Bs + grp * 512, Bw + (size_t)(n0 + r) * K + kt + g * 8);
    }
    __syncthreads();
#pragma unroll
    for (int ks = 0; ks < 2; ++ks) {
      const int c = ks * 4 + lhi;
      bf16x8 af[4], bfr[4];
#pragma unroll
      for (int mf = 0; mf < 4; ++mf) {
        const int r = wm * 64 + mf * 16 + l15;
        af[mf] = *(const bf16x8*)&As[r * 64 + ((c ^ (r & 7)) << 3)];
      }
#pragma unroll
      for (int nf = 0; nf < 4; ++nf) {
        const int r = wn * 64 + nf * 16 + l15;
        bfr[nf] = *(const bf16x8*)&Bs[r * 64 + ((c ^ (r & 7)) << 3)];
      }
#pragma unroll
      for (int mf = 0; mf < 4; ++mf)
#pragma unroll
        for (int nf = 0; nf < 4; ++nf)
          acc[mf][nf] = mfma16(af[mf], bfr[nf], acc[mf][nf]);
    }
    __syncthreads();
  }
#pragma unroll
  for (int nf = 0; nf < 4; ++nf) {
    const int j = n0 + wn * 64 + nf * 16 + l15;
    const float bv = bias[j];
    if constexpr (MODE == 1) {
      const size_t obase = (size_t)(j >> 10) * (4096 * 1024) + (j & 1023);
#pragma unroll
      for (int mf = 0; mf < 4; ++mf)
#pragma unroll
        for (int i = 0; i < 4; ++i) {
          const int row = m0 + wm * 64 + mf * 16 + lhi * 4 + i;
          ((float*)outp)[obase + (size_t)row * 1024] = acc[mf][nf][i] + bv;
        }
    } else {
      if (j < 4096) {               // q,k planes, linear (uniform branch)
        const size_t obase = (size_t)(j >> 10) * (4096 * 1024) + (j & 1023);
#pragma unroll
        for (int mf = 0; mf < 4; ++mf)
#pragma unroll
          for (int i = 0; i < 4; ++i) {
            const int row = m0 + wm * 64 + mf * 16 + lhi * 4 + i;
            ((u16*)outp)[obase + (size_t)row * 1024] = f2b(acc[mf][nf][i] + bv);
          }
      } else {                      // v -> transposed vt[ri][(b*16+h)*64+d][tok]
        const int jv = j - 4096;
        const size_t vb = (size_t)(jv >> 10) * 4194304 +
                          (size_t)((jv >> 6) & 15) * 131072 +
                          (size_t)(jv & 63) * 2048;
#pragma unroll
        for (int mf = 0; mf < 4; ++mf)
#pragma unroll
          for (int i = 0; i < 4; ++i) {
            const int row = m0 + wm * 64 + mf * 16 + lhi * 4 + i;
            const int b2 = row >> 11, tok = row & 2047;
            vtp[vb + (size_t)b2 * 2097152 + tok] = f2b(acc[mf][nf][i] + bv);
          }
      }
    }
  }
}

// ---------------------------------------------------------------------------
// Flash interference attention, round 6: 32x32x16 MFMA, swapped-operand QK^T
// (S^T in regs: lane = one q-row, 16 k-values in-lane -> softmax nearly
// shuffle-free), in-register P->A-frag assembly (cvt_pkrtz + 4 shfl_xor(32)),
// no P LDS round-trip. 4 waves x 32 q-rows (QBLK=128), KVBLK=32 double-
// buffered (layouts identical to round 5), mask pre-scaled into LDS.
// Writes A2[4096][2048] f16: c_r cols 0..1023, c_i cols 1024..2047.
// ---------------------------------------------------------------------------
__global__ __launch_bounds__(256, 2) void attn_kernel(const u16* __restrict__ qkv,
                                                      const u16* __restrict__ vt,
                                                      const float* __restrict__ mask,
                                                      u16* __restrict__ A2) {
  __shared__ __align__(16) u16 KVb[2][4][2048];   // [buf][Kr,Ki (32x64) | Vr,Vi (64x32)]
  __shared__ float maskL[2048];
  const int tid = threadIdx.x, w = tid >> 6, l = tid & 63;
  const int tok = l & 31, hi = l >> 5;
  const int q0 = blockIdx.x * 128;
  const int bh = blockIdx.y;
  const int b = bh >> 4, h = bh & 15;
  const size_t M1 = (size_t)4096 * 1024;
  const u16* qr_b = qkv;
  const u16* qi_b = qkv + M1;
  const u16* kr_b = qkv + 2 * M1;
  const u16* ki_b = qkv + 3 * M1;
  const u16* vtr = vt;
  const u16* vti = vt + (size_t)32 * 64 * 2048;
  constexpr float LOG2E = 1.4426950408889634f;
  constexpr float C2 = 0.015625f * LOG2E;   // 1/HD in log2 domain

  // mask -> LDS, pre-scaled by log2e (b fixed per block)
  {
    const float4* msrc = (const float4*)(mask + (size_t)b * 2048);
    float4 m0 = msrc[tid * 2], m1 = msrc[tid * 2 + 1];
    float4 s0 = {m0.x * LOG2E, m0.y * LOG2E, m0.z * LOG2E, m0.w * LOG2E};
    float4 s1 = {m1.x * LOG2E, m1.y * LOG2E, m1.z * LOG2E, m1.w * LOG2E};
    *(float4*)&maskL[tid * 8] = s0;
    *(float4*)&maskL[tid * 8 + 4] = s1;
  }

  // Q as B-operand frags: lane holds q-row (tok) of this wave's 32-row strip,
  // d-elems kstep*16 + hi*8 + j.
  const size_t qrow = (size_t)(b * 2048 + q0 + w * 32 + tok) * 1024 + h * 64 + hi * 8;
  bf16x8 qr[4], qi[4], qrn[4];
#pragma unroll
  for (int ks = 0; ks < 4; ++ks) {
    qr[ks] = *(const bf16x8*)&qr_b[qrow + ks * 16];
    qi[ks] = *(const bf16x8*)&qi_b[qrow + ks * 16];
    qrn[ks] = qr[ks] ^ (short)0x8000;   // -Qr (f16 sign flip)
  }
  float mrow = -1e30f, srow = 0.f;
  f32x16 o_r[2] = {}, o_i[2] = {};

  auto STAGE = [&](int tile, int bufi) {
    const int k0s = tile * 32;
    if (w < 2) {                       // K mats: [32 keys][64 d]
      const u16* src = w ? ki_b : kr_b;
      u16* dstb = &KVb[bufi][w][0];
#pragma unroll
      for (int it = 0; it < 4; ++it) {
        const int cl = it * 64 + l;
        const int r = cl >> 3;
        const int g = (cl & 7) ^ (r & 7);
        GLD16(dstb + it * 512, src + (size_t)(b * 2048 + k0s + r) * 1024 + h * 64 + g * 8);
      }
    } else {                           // V mats: [64 d][32 tok]
      const u16* src = (w == 3) ? vti : vtr;
      u16* dstb = &KVb[bufi][w][0];
#pragma unroll
      for (int it = 0; it < 4; ++it) {
        const int cl = it * 64 + l;
        const int r = cl >> 2;
        const int g = (cl & 3) ^ ((r >> 1) & 3);
        GLD16(dstb + it * 512, src + (size_t)(bh * 64 + r) * 2048 + k0s + g * 8);
      }
    }
  };

  const int krow = tok * 64;
  const int ksw = tok & 7;

  STAGE(0, 0);
#pragma unroll 2
  for (int kt = 0; kt < 64; ++kt) {
    const int cur = kt & 1;
    const int k0 = kt * 32;
    __syncthreads();                   // implicit vmcnt(0): buf[cur] ready
    if (kt < 63) STAGE(kt + 1, cur ^ 1);
    const u16* Kr = &KVb[cur][0][0];
    const u16* Ki = &KVb[cur][1][0];
    const u16* Vr = &KVb[cur][2][0];
    const u16* Vi = &KVb[cur][3][0];
    // ---- S^T = mfma(K, Q): col = q (tok), rows = k in-lane ----
    f32x16 sr = {}, si = {};
    __builtin_amdgcn_s_setprio(1);
#pragma unroll
    for (int ks = 0; ks < 4; ++ks) {
      const int off = krow + (((ks * 2 + hi) ^ ksw) << 3);
      bf16x8 kfr = *(const bf16x8*)&Kr[off];
      bf16x8 kfi = *(const bf16x8*)&Ki[off];
      sr = mfma32(kfr, qr[ks], sr);
      sr = mfma32(kfi, qi[ks], sr);
      si = mfma32(kfr, qi[ks], si);
      si = mfma32(kfi, qrn[ks], si);
    }
    __builtin_amdgcn_s_setprio(0);
    // ---- scores in log2 domain, mask included ----
    float t[16];
#pragma unroll
    for (int qd = 0; qd < 4; ++qd) {
      const float4 mk = *(const float4*)&maskL[k0 + qd * 8 + hi * 4];
#pragma unroll
      for (int j = 0; j < 4; ++j) {
        const int r = qd * 4 + j;
        const float ss = fmaf(si[r], si[r], sr[r] * sr[r]);
        t[r] = fmaf(ss, C2, ((const float*)&mk)[j]);
      }
    }
    // ---- row max: in-lane tree + 1 cross shfl ----
    float pmax = t[0];
#pragma unroll
    for (int r = 1; r < 16; ++r) pmax = fmaxf(pmax, t[r]);
    pmax = fmaxf(pmax, __shfl_xor(pmax, 32, 64));
    // ---- defer-max rescale (rare) ----
    if (__any(pmax > mrow + 11.f)) {
      const float mn = fmaxf(mrow, pmax);
      const float sc = fexp2(mrow - mn);
      mrow = mn;
      srow *= sc;
#pragma unroll
      for (int r = 0; r < 16; ++r) {
        const float scr = __shfl(sc, (r & 3) + 8 * (r >> 2) + 4 * hi, 64);
        o_r[0][r] *= scr; o_r[1][r] *= scr;
        o_i[0][r] *= scr; o_i[1][r] *= scr;
      }
    }
    // ---- exp + partial sum (deferred reduce) ----
    float p[16];
#pragma unroll
    for (int r = 0; r < 16; ++r) {
      p[r] = fexp2(t[r] - mrow);       // bounded by 2^11
      srow += p[r];
    }
    // ---- P -> A-frags in registers: cvt_pkrtz + 4 shfl_xor(32) ----
    unsigned P[8];
#pragma unroll
    for (int e = 0; e < 8; ++e)
      P[e] = __builtin_bit_cast(unsigned,
               __builtin_amdgcn_cvt_pkrtz(p[2 * e], p[2 * e + 1]));
    const bool h0 = (hi == 0);
    const unsigned r0 = (unsigned)__shfl_xor((int)(h0 ? P[2] : P[0]), 32, 64);
    const unsigned r1 = (unsigned)__shfl_xor((int)(h0 ? P[3] : P[1]), 32, 64);
    const unsigned r2 = (unsigned)__shfl_xor((int)(h0 ? P[6] : P[4]), 32, 64);
    const unsigned r3 = (unsigned)__shfl_xor((int)(h0 ? P[7] : P[5]), 32, 64);
    unsigned fa0[4] = { h0 ? P[0] : r0, h0 ? P[1] : r1, h0 ? r0 : P[2], h0 ? r1 : P[3] };
    unsigned fa1[4] = { h0 ? P[4] : r2, h0 ? P[5] : r3, h0 ? r2 : P[6], h0 ? r3 : P[7] };
    bf16x8 pa0, pa1;
#pragma unroll
    for (int e = 0; e < 4; ++e) {
      ((unsigned*)&pa0)[e] = fa0[e];
      ((unsigned*)&pa1)[e] = fa1[e];
    }
    // ---- PV: O[32q][64d], A = P, B = V^T tiles ----
    __builtin_amdgcn_s_setprio(1);
#pragma unroll
    for (int nf = 0; nf < 2; ++nf) {
      const int dv = nf * 32 + tok;
      const int vsw = (dv >> 1) & 3;
      const int voff0 = dv * 32 + ((hi ^ vsw) << 3);          // kstep 0
      const int voff1 = dv * 32 + (((2 + hi) ^ vsw) << 3);    // kstep 1
      o_r[nf] = mfma32(pa0, *(const bf16x8*)&Vr[voff0], o_r[nf]);
      o_i[nf] = mfma32(pa0, *(const bf16x8*)&Vi[voff0], o_i[nf]);
      o_r[nf] = mfma32(pa1, *(const bf16x8*)&Vr[voff1], o_r[nf]);
      o_i[nf] = mfma32(pa1, *(const bf16x8*)&Vi[voff1], o_i[nf]);
    }
    __builtin_amdgcn_s_setprio(0);
  }
  // ---- final: full row sum, redistribute inv per o-row, store ----
  const float stot = srow + __shfl_xor(srow, 32, 64);
  const float invq = 1.f / stot;
  const int rowbase = b * 2048 + q0 + w * 32;
#pragma unroll
  for (int r = 0; r < 16; ++r) {
    const int qr2 = (r & 3) + 8 * (r >> 2) + 4 * hi;
    const float iv = __shfl(invq, qr2, 64);
    const size_t rw = (size_t)(rowbase + qr2) * 2048;
#pragma unroll
    for (int nf = 0; nf < 2; ++nf) {
      const int col = h * 64 + nf * 32 + tok;
      A2[rw + col] = f2b(o_r[nf][r] * iv);
      A2[rw + 1024 + col] = f2b(o_i[nf][r] * iv);
    }
  }
}

// ---------------------------------------------------------------------------
extern "C" void kernel_launch(void* const* d_in, const int* in_sizes, int n_in,
                              void* d_out, int out_size, void* d_ws, size_t ws_size,
                              hipStream_t stream) {
  (void)in_sizes; (void)n_in; (void)out_size; (void)ws_size;
  const float* x_r  = (const float*)d_in[0];
  const float* x_i  = (const float*)d_in[1];
  const float* mask = (const float*)d_in[2];

  PWArgs pw;
  pw.Wr[0] = (const float*)d_in[3];  pw.br[0] = (const float*)d_in[4];
  pw.Wi[0] = (const float*)d_in[5];  pw.bi[0] = (const float*)d_in[6];
  pw.Wr[1] = (const float*)d_in[7];  pw.br[1] = (const float*)d_in[8];
  pw.Wi[1] = (const float*)d_in[9];  pw.bi[1] = (const float*)d_in[10];
  pw.Wr[2] = (const float*)d_in[11]; pw.br[2] = (const float*)d_in[12];
  pw.Wi[2] = (const float*)d_in[13]; pw.bi[2] = (const float*)d_in[14];
  pw.Wr[3] = (const float*)d_in[15]; pw.br[3] = (const float*)d_in[16];
  pw.Wi[3] = (const float*)d_in[17]; pw.bi[3] = (const float*)d_in[18];

  char* ws = (char*)d_ws;
  u16* A     = (u16*)(ws);                  // 16 MB: A1, later A2
  u16* B1    = (u16*)(ws + (16u << 20));    // 24 MB packed QKV weights (dead after gemm1)
  u16* B2    = (u16*)(ws + (16u << 20));    // 8 MB packed O weights (packed after gemm1)
  u16* qkvp  = (u16*)(ws + (40u << 20));    // 32 MB: qr,qi,kr,ki planes
  u16* vtp   = (u16*)(ws + (72u << 20));    // 16 MB: V transposed [2][32bh][64][2048]
  float* bias1 = (float*)(ws + (88u << 20));
  float* bias2 = (float*)(ws + (88u << 20) + (1u << 15));

  pack_x_kernel<<<4096, 256, 0, stream>>>(A, x_r, x_i);
  pack_w_all<<<dim3(1024, 6), 256, 0, stream>>>(pw, 0, B1, B2, bias1, bias2);

  gemm_bt<0><<<dim3(48, 32), 256, 0, stream>>>(A, B1, bias1, qkvp, vtp);

  pack_w_all<<<dim3(1024, 2), 256, 0, stream>>>(pw, 6, B1, B2, bias1, bias2);

  attn_kernel<<<dim3(16, 32), 256, 0, stream>>>(qkvp, vtp, mask, A);

  gemm_bt<1><<<dim3(16, 32), 256, 0, stream>>>(A, B2, bias2, d_out, nullptr);
}